// Round 3
// baseline (798.438 us; speedup 1.0000x reference)
//
#include <hip/hip_runtime.h>
#include <stdint.h>

// VQ-VAE forward on MI355X — replicates the numpy fp32 reference bit-for-bit
// where it matters for argmin.
// z_e: [64, 256, 32, 32] f32 ; emb: [1024, 256] f32
// out: z_q_st (16777216) | loss (1) | perplexity (1) | idx (65536, as float)
//
// Reference computes dists = xnorm + enorm - 2*(x@emb.T) in fp32: scores ~256
// quantized at ulp ~1.5e-5..3e-5, ties resolved by lowest index. We replicate:
//  - xnorm/enorm via numpy pairwise-sum tree (contract off, no FMA),
//  - s = fl32(fl32(xn+en) - 2*dot), packed (monotone(s), idx) argmin,
//  - fp32-FMA dots as fast path; rows with quantized top-2 gap <= 1.25e-4
//    get full-row rescore with fp64 dots (removes our dot-order error).
//
// ws layout (bytes):
//   [0,       4096)     enorm   float[1024]     (np-pairwise ||e||^2)
//   [4096,    266240)   xnorm   float[65536]    (np-pairwise ||x||^2)
//   [266240,  4460544)  top2    u64[4][65536][2]
//   [4460544, 4722688)  fidx    int[65536]
//   [4722688, 4726784)  counts  int[1024]
//   [4726784, 4726788)  loss_sum float
//   [4726788, 4726792)  amb_count int
//   [4726792, 4792328)  amb     int[16384]

#define D_DIM   256
#define K_CODES 1024
#define N_ROWS  65536
#define TM      64
#define TK      256
#define DD      32
#define N_ELEM  16777216
#define IDX_OFF 16777218
#define FLAG_MARGIN 1.25e-4f
#define AMB_CAP 16384

__device__ __forceinline__ unsigned int mono(float s) {
    unsigned int u = __float_as_uint(s);
    return (u & 0x80000000u) ? ~u : (u | 0x80000000u);
}
__device__ __forceinline__ float unmono(unsigned int u) {
    return __uint_as_float((u & 0x80000000u) ? (u & 0x7FFFFFFFu) : ~u);
}

// numpy pairwise sum of squares, n=256: two 128-halves, each 8 rotating
// accumulators; NO FMA (contract off) to match np elementwise x*x then sum.
__global__ void enorm_np_kernel(const float* __restrict__ emb,
                                float* __restrict__ enorm) {
#pragma clang fp contract(off)
    int k = blockIdx.x * 256 + threadIdx.x;
    const float* p = emb + (size_t)k * D_DIM;
    float half[2];
    #pragma unroll
    for (int h = 0; h < 2; ++h) {
        const float* q = p + h * 128;
        float r[8];
        #pragma unroll
        for (int j = 0; j < 8; ++j) { float x = q[j]; r[j] = x * x; }
        for (int i = 8; i < 128; i += 8)
            #pragma unroll
            for (int j = 0; j < 8; ++j) { float x = q[i + j]; r[j] = r[j] + x * x; }
        half[h] = ((r[0] + r[1]) + (r[2] + r[3])) + ((r[4] + r[5]) + (r[6] + r[7]));
    }
    enorm[k] = half[0] + half[1];
}

__global__ void xnorm_np_kernel(const float* __restrict__ z_e,
                                float* __restrict__ xnorm) {
#pragma clang fp contract(off)
    int row = blockIdx.x * 256 + threadIdx.x;
    int b = row >> 10, hw = row & 1023;
    const float* p = z_e + (size_t)b * 262144 + hw;
    float half[2];
    #pragma unroll
    for (int h = 0; h < 2; ++h) {
        float r[8];
        #pragma unroll
        for (int j = 0; j < 8; ++j) {
            float x = p[(size_t)(h * 128 + j) * 1024]; r[j] = x * x;
        }
        for (int i = 8; i < 128; i += 8)
            #pragma unroll
            for (int j = 0; j < 8; ++j) {
                float x = p[(size_t)(h * 128 + i + j) * 1024]; r[j] = r[j] + x * x;
            }
        half[h] = ((r[0] + r[1]) + (r[2] + r[3])) + ((r[4] + r[5]) + (r[6] + r[7]));
    }
    xnorm[row] = half[0] + half[1];
}

// Block: 64 rows x 256 codes. 256 threads = 32 tx * 8 ty. Thread tile 8x8.
__launch_bounds__(256, 2)
__global__ void dist_kernel(const float* __restrict__ z_e,
                            const float* __restrict__ emb,
                            const float* __restrict__ enorm,
                            const float* __restrict__ xnorm,
                            unsigned long long* __restrict__ top2) {
    __shared__ __align__(16) char smem[40960];
    float* Xs = (float*)smem;                 // [dd][j]  DD*TM (8KB)
    float* Es = (float*)(smem + 8192);        // [dd][c]  DD*TK (32KB)
    unsigned long long* red = (unsigned long long*)smem;  // overlay, 32*130

    const int tid = threadIdx.x;
    const int tx = tid & 31, ty = tid >> 5;
    const int rcb = blockIdx.x;
    const int b   = rcb >> 4;
    const int hw0 = (rcb & 15) << 6;
    const int k0  = blockIdx.y * TK;

    float acc[8][8];
    #pragma unroll
    for (int r = 0; r < 8; ++r)
        #pragma unroll
        for (int q = 0; q < 8; ++q) acc[r][q] = 0.f;

    const float* zbase = z_e + (size_t)b * 262144 + hw0;
    const float* ebase = emb + (size_t)(k0 + tid) * D_DIM;

    for (int d0 = 0; d0 < D_DIM; d0 += DD) {
        #pragma unroll
        for (int it = 0; it < 2; ++it) {
            int f  = tid + it * 256;
            int dd = f >> 4;
            int j4 = (f & 15) << 2;
            float4 v = *(const float4*)(zbase + (size_t)(d0 + dd) * 1024 + j4);
            *(float4*)(&Xs[dd * TM + j4]) = v;
        }
        {
            const float* ep = ebase + d0;
            #pragma unroll
            for (int dq = 0; dq < 8; ++dq) {
                float4 v = *(const float4*)(ep + dq * 4);
                Es[(dq * 4 + 0) * TK + tid] = v.x;
                Es[(dq * 4 + 1) * TK + tid] = v.y;
                Es[(dq * 4 + 2) * TK + tid] = v.z;
                Es[(dq * 4 + 3) * TK + tid] = v.w;
            }
        }
        __syncthreads();

        #pragma unroll 2
        for (int dd = 0; dd < DD; ++dd) {
            float4 xa = *(const float4*)(&Xs[dd * TM + 8 * ty]);
            float4 xb = *(const float4*)(&Xs[dd * TM + 8 * ty + 4]);
            float4 ea = *(const float4*)(&Es[dd * TK + 4 * tx]);
            float4 eb = *(const float4*)(&Es[dd * TK + 128 + 4 * tx]);
            float xr[8] = {xa.x, xa.y, xa.z, xa.w, xb.x, xb.y, xb.z, xb.w};
            float er[8] = {ea.x, ea.y, ea.z, ea.w, eb.x, eb.y, eb.z, eb.w};
            #pragma unroll
            for (int r = 0; r < 8; ++r)
                #pragma unroll
                for (int q = 0; q < 8; ++q)
                    acc[r][q] += xr[r] * er[q];
        }
        __syncthreads();
    }

    // np-replicated score: s = fl32(fl32(xn + en_k) - 2*dot)
    float4 ena = *(const float4*)(enorm + k0 + 4 * tx);
    float4 enb = *(const float4*)(enorm + k0 + 128 + 4 * tx);
    float en[8] = {ena.x, ena.y, ena.z, ena.w, enb.x, enb.y, enb.z, enb.w};
    const float* xnp = xnorm + rcb * 64 + 8 * ty;
    float xnr[8];
    #pragma unroll
    for (int r = 0; r < 8; ++r) xnr[r] = xnp[r];

    #pragma unroll
    for (int r = 0; r < 8; ++r) {
        unsigned long long p1 = ~0ull, p2 = ~0ull;
        #pragma unroll
        for (int q = 0; q < 8; ++q) {
            int k = k0 + ((q < 4) ? (4 * tx + q) : (128 + 4 * tx + (q - 4)));
            float t = xnr[r] + en[q];            // rounds (np broadcast add)
            float s = t - 2.f * acc[r][q];       // 2*acc exact; one rounding
            unsigned long long p = ((unsigned long long)mono(s) << 32) | (unsigned int)k;
            if (p < p1) { p2 = p1; p1 = p; } else if (p < p2) { p2 = p; }
        }
        red[tx * 130 + (8 * ty + r) * 2 + 0] = p1;
        red[tx * 130 + (8 * ty + r) * 2 + 1] = p2;
    }
    __syncthreads();

    if (tid < 64) {
        const int row = tid;
        unsigned long long p1 = ~0ull, p2 = ~0ull;
        for (int t = 0; t < 32; ++t) {
            unsigned long long a = red[t * 130 + row * 2 + 0];
            unsigned long long c = red[t * 130 + row * 2 + 1];
            if (a < p1) { p2 = p1; p1 = a; } else if (a < p2) p2 = a;
            if (c < p1) { p2 = p1; p1 = c; } else if (c < p2) p2 = c;
        }
        size_t o = ((size_t)blockIdx.y * N_ROWS + (size_t)rcb * 64 + row) * 2;
        top2[o + 0] = p1;
        top2[o + 1] = p2;
    }
}

__global__ void resolve_kernel(const unsigned long long* __restrict__ top2,
                               int* __restrict__ fidx,
                               int* __restrict__ amb,
                               int* __restrict__ amb_count) {
    int row = blockIdx.x * 256 + threadIdx.x;
    unsigned long long p1 = ~0ull, p2 = ~0ull;
    #pragma unroll
    for (int c = 0; c < 4; ++c) {
        size_t o = ((size_t)c * N_ROWS + row) * 2;
        unsigned long long a = top2[o + 0];
        unsigned long long b = top2[o + 1];
        if (a < p1) { p2 = p1; p1 = a; } else if (a < p2) p2 = a;
        if (b < p1) { p2 = p1; p1 = b; } else if (b < p2) p2 = b;
    }
    fidx[row] = (int)(p1 & 0xFFFFFFFFull);
    float s1 = unmono((unsigned int)(p1 >> 32));
    float s2 = unmono((unsigned int)(p2 >> 32));
    if (s2 - s1 <= FLAG_MARGIN) {
        int slot = atomicAdd(amb_count, 1);
        if (slot < AMB_CAP) amb[slot] = row;
    }
}

// Full-row rescore with fp64 dots through the np fp32 quantization pipeline.
__launch_bounds__(256)
__global__ void rescue_kernel(const float* __restrict__ z_e,
                              const float* __restrict__ emb,
                              const float* __restrict__ xnorm,
                              const float* __restrict__ enorm,
                              const int* __restrict__ amb,
                              const int* __restrict__ amb_count,
                              int* __restrict__ fidx) {
    __shared__ __align__(16) float xs[256];
    __shared__ unsigned long long rmin[256];
    const int tid = threadIdx.x;
    int cnt = *amb_count;
    if (cnt > AMB_CAP) cnt = AMB_CAP;
    for (int e = blockIdx.x; e < cnt; e += gridDim.x) {
        int row = amb[e];
        int b = row >> 10, hw = row & 1023;
        xs[tid] = z_e[(size_t)b * 262144 + (size_t)tid * 1024 + hw];
        __syncthreads();
        float xn = xnorm[row];
        unsigned long long best = ~0ull;
        #pragma unroll
        for (int kk = 0; kk < 4; ++kk) {
            int k = kk * 256 + tid;
            const float* ep = emb + (size_t)k * D_DIM;
            double dot = 0.0;
            for (int d = 0; d < D_DIM; d += 4) {
                float4 ev = *(const float4*)(ep + d);
                float4 xv = *(const float4*)(&xs[d]);
                dot += (double)xv.x * (double)ev.x + (double)xv.y * (double)ev.y
                     + (double)xv.z * (double)ev.z + (double)xv.w * (double)ev.w;
            }
            float d32 = (float)dot;              // correctly-rounded dot
            float t = xn + enorm[k];
            float s = t - 2.f * d32;
            unsigned long long p = ((unsigned long long)mono(s) << 32) | (unsigned int)k;
            if (p < best) best = p;
        }
        rmin[tid] = best;
        __syncthreads();
        for (int st = 128; st > 0; st >>= 1) {
            if (tid < st && rmin[tid + st] < rmin[tid]) rmin[tid] = rmin[tid + st];
            __syncthreads();
        }
        if (tid == 0) fidx[row] = (int)(rmin[0] & 0xFFFFFFFFull);
        __syncthreads();
    }
}

__global__ void epilogue_kernel(const float* __restrict__ z_e,
                                const float* __restrict__ emb,
                                const int* __restrict__ fidx,
                                float* __restrict__ out,
                                int* __restrict__ counts,
                                float* __restrict__ loss_sum) {
    __shared__ int   kb[64];
    __shared__ float rs[256];
    const int tid = threadIdx.x;
    const int rcb = blockIdx.x;
    const int b   = rcb >> 4;
    const int hw0 = (rcb & 15) << 6;

    if (tid < 64) {
        int k = fidx[rcb * 64 + tid];
        kb[tid] = k;
        out[(size_t)IDX_OFF + (size_t)rcb * 64 + tid] = (float)k;
        atomicAdd(&counts[k], 1);
    }
    __syncthreads();

    const int j = tid & 63, dq = tid >> 6;
    const float* er = emb + (size_t)kb[j] * D_DIM;
    const size_t base = (size_t)b * 262144 + hw0 + j;
    float ls = 0.f;
    #pragma unroll 4
    for (int d = dq; d < D_DIM; d += 4) {
        float zq = er[d];
        size_t off = base + (size_t)d * 1024;
        float x = z_e[off];
        out[off] = zq;
        float df = zq - x;
        ls += df * df;
    }
    rs[tid] = ls;
    __syncthreads();
    for (int s = 128; s > 0; s >>= 1) {
        if (tid < s) rs[tid] += rs[tid + s];
        __syncthreads();
    }
    if (tid == 0) atomicAdd(loss_sum, rs[0]);
}

__global__ void finalize_kernel(const int* __restrict__ counts,
                                const float* __restrict__ loss_sum,
                                float* __restrict__ out) {
    __shared__ float rs[256];
    const int tid = threadIdx.x;
    float s = 0.f;
    for (int k = tid; k < K_CODES; k += 256) {
        float p = (float)counts[k] / 65536.0f;
        s += p * logf(p + 1e-10f);
    }
    rs[tid] = s;
    __syncthreads();
    for (int st = 128; st > 0; st >>= 1) {
        if (tid < st) rs[tid] += rs[tid + st];
        __syncthreads();
    }
    if (tid == 0) {
        out[N_ELEM]     = loss_sum[0] * 1.25f / 16777216.0f;
        out[N_ELEM + 1] = expf(-rs[0]);
    }
}

extern "C" void kernel_launch(void* const* d_in, const int* in_sizes, int n_in,
                              void* d_out, int out_size, void* d_ws, size_t ws_size,
                              hipStream_t stream) {
    const float* z_e = (const float*)d_in[0];
    const float* emb = (const float*)d_in[1];
    float* out = (float*)d_out;
    char*  ws  = (char*)d_ws;

    float*              enorm    = (float*)ws;
    float*              xnorm    = (float*)(ws + 4096);
    unsigned long long* top2     = (unsigned long long*)(ws + 266240);
    int*                fidx     = (int*)(ws + 4460544);
    int*                counts   = (int*)(ws + 4722688);
    float*              loss_sum = (float*)(ws + 4726784);
    int*                amb_cnt  = (int*)(ws + 4726788);
    int*                amb      = (int*)(ws + 4726792);

    hipMemsetAsync(counts, 0, 4104, stream);   // counts + loss_sum + amb_count

    enorm_np_kernel<<<K_CODES / 256, 256, 0, stream>>>(emb, enorm);
    xnorm_np_kernel<<<N_ROWS / 256, 256, 0, stream>>>(z_e, xnorm);
    dist_kernel<<<dim3(N_ROWS / TM, K_CODES / TK), 256, 0, stream>>>(z_e, emb, enorm, xnorm, top2);
    resolve_kernel<<<N_ROWS / 256, 256, 0, stream>>>(top2, fidx, amb, amb_cnt);
    rescue_kernel<<<1024, 256, 0, stream>>>(z_e, emb, xnorm, enorm, amb, amb_cnt, fidx);
    epilogue_kernel<<<N_ROWS / TM, 256, 0, stream>>>(z_e, emb, fidx, out, counts, loss_sum);
    finalize_kernel<<<1, 256, 0, stream>>>(counts, loss_sum, out);
}